// Round 13
// baseline (184.236 us; speedup 1.0000x reference)
//
#include <hip/hip_runtime.h>

#define NN 100000      // nodes
#define NE 1600000     // edges
#define D  64          // feature dim
#define NBK 512        // dst buckets
#define NPB 196        // nodes per bucket; 512*196 = 100352 >= NN
#define CAP 4096       // slots per bucket (mean 3125, sd 56 -> 17 sigma)
#define CHUNK 2048     // edges per bin block (256 thr); R11: 8192 -> 7% occ
#define NCH ((NE + CHUNK - 1) / CHUNK)   // 782 bin blocks

// ---- workspace: cursor[NBK] ints | bins[NBK*CAP] ints | xb[NN*D] ushort ----

typedef unsigned short u16;
typedef __attribute__((ext_vector_type(8))) short bf16x8;   // 4 VGPRs
typedef __attribute__((ext_vector_type(4))) float f32x4;

__device__ __forceinline__ u16 f32_to_bf16_rn(float f) {
    unsigned u = __float_as_uint(f);
    return (u16)((u + 0x7FFF + ((u >> 16) & 1)) >> 16);   // round-nearest-even
}
__device__ __forceinline__ float bf16_to_f32(u16 h) {
    return __uint_as_float(((unsigned)h) << 16);          // exact
}

// x (fp32) -> xb (bf16), vectorized float4 -> ushort4. (R10/R11-proven form.)
__global__ __launch_bounds__(256) void cvt_kernel(const float* __restrict__ x,
                                                  u16* __restrict__ xb) {
    int i = (blockIdx.x * blockDim.x + threadIdx.x) * 4;   // NN*D % 4 == 0
    if (i < NN * D) {
        float4 v = *(const float4*)(x + i);
        ushort4 o;
        o.x = f32_to_bf16_rn(v.x);
        o.y = f32_to_bf16_rn(v.y);
        o.z = f32_to_bf16_rn(v.z);
        o.w = f32_to_bf16_rn(v.w);
        *(ushort4*)(xb + i) = o;
    }
}

// Direct binning: LDS per-bucket counts, one global atomic per (block,bucket)
// reserves a range, packed (loc<<17)|src writes. 782 blocks (R11: 196 blocks
// = 7% occupancy, latency-bound). Runs avg 4 ints — ~2x write amplification
// accepted for 4x wave parallelism.
__global__ __launch_bounds__(256) void bin_kernel(const int* __restrict__ ei,
                                                  int* __restrict__ cursor,
                                                  int* __restrict__ bins) {
    __shared__ int lc[NBK];
    __shared__ int lbase[NBK];
    const int t = threadIdx.x;
    const int base = blockIdx.x * CHUNK;

    for (int i = t; i < NBK; i += 256) lc[i] = 0;
    __syncthreads();
    #pragma unroll
    for (int j = 0; j < CHUNK / 256; ++j) {
        int e = base + t + j * 256;
        if (e < NE) atomicAdd(&lc[(unsigned)ei[NE + e] / NPB], 1);
    }
    __syncthreads();
    for (int i = t; i < NBK; i += 256) {
        int c = lc[i];
        lbase[i] = c ? atomicAdd(&cursor[i], c) : 0;
        lc[i] = 0;                 // reuse as local offset counter
    }
    __syncthreads();
    #pragma unroll
    for (int j = 0; j < CHUNK / 256; ++j) {
        int e = base + t + j * 256;
        if (e < NE) {
            int src = ei[e];
            int dst = ei[NE + e];
            int b   = (unsigned)dst / NPB;
            int loc = dst - b * NPB;                  // < 196
            int o   = atomicAdd(&lc[b], 1);
            int pos = lbase[b] + o;
            if (pos < CAP)                            // 17-sigma safety clamp
                bins[b * CAP + pos] = (loc << 17) | src;   // src < 2^17
        }
    }
}

// One 1024-thread block per bucket: LDS counting-sort by local node id, then
// quarter-wave register gather: lane = (g=lane>>4 edge subgroup, m=lane&15
// dim group); one wave-inst loads 4 edges x 128B (ushort4/lane). Cross-group
// merge via 2 shfl_xor butterflies per node. R11: agg was issue-count-bound
// (44us vs 19us BW floor, VALUBusy 43%).
__global__ __launch_bounds__(1024) void agg_kernel(const float* __restrict__ x,
                                                   const u16* __restrict__ xb,
                                                   const float* __restrict__ eps,
                                                   const int* __restrict__ cursor,
                                                   const int* __restrict__ bins,
                                                   float* __restrict__ out) {
    __shared__ int sorted[CAP];    // 16 KB
    __shared__ int tmp[256];
    __shared__ int off[256];       // off[r] = start of node r; off[196] == n
    __shared__ int cur[256];
    const int b    = blockIdx.x;
    const int t    = threadIdx.x;
    const int lane = t & 63;
    const int w    = t >> 6;       // 16 waves
    const int base = b * CAP;
    const int n    = min(cursor[b], CAP);
    const float e1 = 1.0f + *eps;

    // ---- counting sort by local node id (R11-proven) ----
    if (t < 256) tmp[t] = 0;
    __syncthreads();
    for (int i = t; i < n; i += 1024)
        atomicAdd(&tmp[bins[base + i] >> 17], 1);
    __syncthreads();
    int v = (t < 256) ? tmp[t] : 0;
    for (int o = 1; o < 256; o <<= 1) {            // inclusive scan
        int u = (t < 256 && t >= o) ? tmp[t - o] : 0;
        __syncthreads();
        if (t < 256) tmp[t] += u;
        __syncthreads();
    }
    if (t < 256) { off[t] = tmp[t] - v; cur[t] = tmp[t] - v; }
    __syncthreads();
    for (int i = t; i < n; i += 1024) {
        int pk  = bins[base + i];
        int pos = atomicAdd(&cur[pk >> 17], 1);
        sorted[pos] = pk & 0x1FFFF;
    }
    __syncthreads();

    // ---- quarter-wave gather: 4 edges per wave iteration ----
    const int g = lane >> 4;       // edge subgroup 0..3
    const int m = lane & 15;       // dim group: dims 4m..4m+3
    #pragma unroll
    for (int j = 0; j < 13; ++j) {
        int r = w + 16 * j;                        // 16 waves x 13 >= 196
        if (r < NPB) {
            int node = b * NPB + r;
            if (node < NN) {
                float4 acc = {0.f, 0.f, 0.f, 0.f};
                const int pe = off[r + 1];
                for (int p = off[r]; p < pe; p += 4) {
                    int pi  = p + g;
                    int src = sorted[pi < pe ? pi : p];   // dup-safe tail
                    ushort4 u = *(const ushort4*)(xb + src * D + 4 * m);
                    float sel = (pi < pe) ? 1.0f : 0.0f;
                    acc.x = fmaf(sel, bf16_to_f32(u.x), acc.x);
                    acc.y = fmaf(sel, bf16_to_f32(u.y), acc.y);
                    acc.z = fmaf(sel, bf16_to_f32(u.z), acc.z);
                    acc.w = fmaf(sel, bf16_to_f32(u.w), acc.w);
                }
                // butterfly over g (lane bits 4,5)
                acc.x += __shfl_xor(acc.x, 16, 64);
                acc.y += __shfl_xor(acc.y, 16, 64);
                acc.z += __shfl_xor(acc.z, 16, 64);
                acc.w += __shfl_xor(acc.w, 16, 64);
                acc.x += __shfl_xor(acc.x, 32, 64);
                acc.y += __shfl_xor(acc.y, 32, 64);
                acc.z += __shfl_xor(acc.z, 32, 64);
                acc.w += __shfl_xor(acc.w, 32, 64);
                if (g == 0) {                      // self term + store, 16 lanes
                    float4 s = *(const float4*)(x + node * D + 4 * m);
                    acc.x = fmaf(e1, s.x, acc.x);
                    acc.y = fmaf(e1, s.y, acc.y);
                    acc.z = fmaf(e1, s.z, acc.z);
                    acc.w = fmaf(e1, s.w, acc.w);
                    *(float4*)(out + node * D + 4 * m) = acc;
                }
            }
        }
    }
}

// MFMA MLP (R11-proven): one wave per 16-node tile, bf16 16x16x32 MFMA,
// layer1 C-layout -> wave-private LDS -> layer2 A-layout, in-place on d_out.
__global__ __launch_bounds__(256, 2) void mlp_mfma_kernel(
        float* __restrict__ h,
        const float* __restrict__ W1, const float* __restrict__ b1,
        const float* __restrict__ W2, const float* __restrict__ b2) {
    __shared__ u16 lds[4][16 * 72];   // per-wave tile, row stride 72 u16
    const int lane = threadIdx.x & 63;
    const int wv   = threadIdx.x >> 6;
    const int m    = lane & 15;
    const int q    = lane >> 4;
    u16* tile = &lds[wv][0];

    bf16x8 wb1[4][2], wb2[4][2];
    #pragma unroll
    for (int t = 0; t < 4; ++t)
        #pragma unroll
        for (int s = 0; s < 2; ++s) {
            bf16x8 f1, f2;
            #pragma unroll
            for (int j = 0; j < 8; ++j) {
                int k = s * 32 + q * 8 + j;
                int nn = t * 16 + m;
                f1[j] = (short)f32_to_bf16_rn(W1[k * D + nn]);
                f2[j] = (short)f32_to_bf16_rn(W2[k * D + nn]);
            }
            wb1[t][s] = f1;
            wb2[t][s] = f2;
        }
    float bias1[4], bias2[4];
    #pragma unroll
    for (int t = 0; t < 4; ++t) {
        bias1[t] = b1[t * 16 + m];
        bias2[t] = b2[t * 16 + m];
    }

    const int wave = blockIdx.x * 4 + wv;
    const int nw   = gridDim.x * 4;
    for (int ti = wave; ti < NN / 16; ti += nw) {
        const int rowbase = ti * 16;

        bf16x8 a1f[2];
        #pragma unroll
        for (int s = 0; s < 2; ++s) {
            const float* p = h + (rowbase + m) * D + s * 32 + q * 8;
            float4 v0 = *(const float4*)p;
            float4 v1 = *(const float4*)(p + 4);
            bf16x8 f;
            f[0] = (short)f32_to_bf16_rn(v0.x);
            f[1] = (short)f32_to_bf16_rn(v0.y);
            f[2] = (short)f32_to_bf16_rn(v0.z);
            f[3] = (short)f32_to_bf16_rn(v0.w);
            f[4] = (short)f32_to_bf16_rn(v1.x);
            f[5] = (short)f32_to_bf16_rn(v1.y);
            f[6] = (short)f32_to_bf16_rn(v1.z);
            f[7] = (short)f32_to_bf16_rn(v1.w);
            a1f[s] = f;
        }

        #pragma unroll
        for (int t = 0; t < 4; ++t) {
            f32x4 c = {0.f, 0.f, 0.f, 0.f};
            c = __builtin_amdgcn_mfma_f32_16x16x32_bf16(a1f[0], wb1[t][0], c, 0, 0, 0);
            c = __builtin_amdgcn_mfma_f32_16x16x32_bf16(a1f[1], wb1[t][1], c, 0, 0, 0);
            #pragma unroll
            for (int r = 0; r < 4; ++r) {
                float vv = fmaxf(c[r] + bias1[t], 0.0f);
                tile[(q * 4 + r) * 72 + t * 16 + m] = f32_to_bf16_rn(vv);
            }
        }

        bf16x8 a2f[2];
        #pragma unroll
        for (int s = 0; s < 2; ++s)
            a2f[s] = *(const bf16x8*)&tile[m * 72 + s * 32 + q * 8];

        #pragma unroll
        for (int t = 0; t < 4; ++t) {
            f32x4 c = {0.f, 0.f, 0.f, 0.f};
            c = __builtin_amdgcn_mfma_f32_16x16x32_bf16(a2f[0], wb2[t][0], c, 0, 0, 0);
            c = __builtin_amdgcn_mfma_f32_16x16x32_bf16(a2f[1], wb2[t][1], c, 0, 0, 0);
            #pragma unroll
            for (int r = 0; r < 4; ++r)
                h[(rowbase + q * 4 + r) * D + t * 16 + m] = c[r] + bias2[t];
        }
    }
}

extern "C" void kernel_launch(void* const* d_in, const int* in_sizes, int n_in,
                              void* d_out, int out_size, void* d_ws, size_t ws_size,
                              hipStream_t stream) {
    const float* x   = (const float*)d_in[0];
    const int*   ei  = (const int*)d_in[1];
    const float* W1  = (const float*)d_in[2];
    const float* b1  = (const float*)d_in[3];
    const float* W2  = (const float*)d_in[4];
    const float* b2  = (const float*)d_in[5];
    const float* eps = (const float*)d_in[6];
    float*       out = (float*)d_out;

    int* cursor = (int*)d_ws;
    int* bins   = cursor + NBK;
    u16* xb     = (u16*)(bins + NBK * CAP);

    hipMemsetAsync(cursor, 0, NBK * sizeof(int), stream);
    cvt_kernel<<<(NN * D / 4 + 255) / 256, 256, 0, stream>>>(x, xb);
    bin_kernel<<<NCH, 256, 0, stream>>>(ei, cursor, bins);
    agg_kernel<<<NBK, 1024, 0, stream>>>(x, xb, eps, cursor, bins, out);
    mlp_mfma_kernel<<<1024, 256, 0, stream>>>(out, W1, b1, W2, b2);
}